// Round 8
// baseline (217.316 us; speedup 1.0000x reference)
//
#include <hip/hip_runtime.h>
#include <math.h>
#include <stddef.h>

#define HQ   16
#define HKV  8
#define DH   128
#define HID  2048
#define CC   16384
#define NCH  64             // flash chunks of 256: 64*256 = 16384 = CC
#define CHUNK 256

// d_out layout (FLOAT32, 4096 elements): [attn 2048][k_new 8*128][v 8*128]

// ---- K1: QKV projections. One wave per output element.
// raw[0..2047]=q (16x128), [2048..3071]=k (8x128), [3072..4095]=v (8x128)
__global__ __launch_bounds__(256, 4)
void k_qkv(const float* __restrict__ x,
           const float* __restrict__ Wq,
           const float* __restrict__ Wk,
           const float* __restrict__ Wv,
           float* __restrict__ raw){
  int wave = threadIdx.x >> 6, lane = threadIdx.x & 63;
  int e = blockIdx.x * 4 + wave;
  const float* W;
  if (e < 2048)      W = Wq + (size_t)e * HID;
  else if (e < 3072) W = Wk + (size_t)(e - 2048) * HID;
  else               W = Wv + (size_t)(e - 3072) * HID;
  // batch ALL weight loads first: 8 float4 in flight (the HBM stream)
  float4 w[8];
  #pragma unroll
  for (int j = 0; j < 4; ++j){
    int base = (j * 64 + lane) * 8;
    w[2*j]   = *(const float4*)(W + base);
    w[2*j+1] = *(const float4*)(W + base + 4);
  }
  float acc = 0.f;
  #pragma unroll
  for (int j = 0; j < 4; ++j){
    int base = (j * 64 + lane) * 8;
    float4 a0 = *(const float4*)(x + base);      // L1/L2-hot (shared by all waves)
    float4 a1 = *(const float4*)(x + base + 4);
    acc += a0.x*w[2*j].x + a0.y*w[2*j].y + a0.z*w[2*j].z + a0.w*w[2*j].w
         + a1.x*w[2*j+1].x + a1.y*w[2*j+1].y + a1.z*w[2*j+1].z + a1.w*w[2*j+1].w;
  }
  #pragma unroll
  for (int off = 32; off; off >>= 1) acc += __shfl_down(acc, off, 64);
  if (lane == 0) raw[e] = acc;
}

// ---- K2: RMSNorm + RoPE (q,k), v passthrough.
__global__ void k_normrope(const float* __restrict__ raw,
                           const float* __restrict__ cosb,
                           const float* __restrict__ sinb,
                           const float* __restrict__ qw,
                           const float* __restrict__ kw,
                           float* __restrict__ qf,
                           float* __restrict__ kf,
                           float* __restrict__ out){
  __shared__ float lds[DH];
  __shared__ float wsum[2];
  int b = blockIdx.x, t = threadIdx.x;
  if (b >= 24){  // v copy to d_out
    int h = b - 24;
    out[3072 + h * DH + t] = raw[3072 + h * DH + t];
    return;
  }
  bool isq = (b < 16);
  int h = isq ? b : b - 16;
  float val = isq ? raw[h * DH + t] : raw[2048 + h * DH + t];
  float ss = val * val;
  #pragma unroll
  for (int off = 32; off; off >>= 1) ss += __shfl_down(ss, off, 64);
  if ((t & 63) == 0) wsum[t >> 6] = ss;
  __syncthreads();
  float rms = sqrtf((wsum[0] + wsum[1]) / 128.f + 1e-6f);
  float w = isq ? qw[t] : kw[t];
  float normed = val / rms * w;
  lds[t] = normed;
  __syncthreads();
  float rot = (t < 64) ? -lds[t + 64] : lds[t - 64];
  float res = normed * cosb[t] + rot * sinb[t];
  if (isq) qf[h * DH + t] = res;
  else { kf[h * DH + t] = res; out[2048 + h * DH + t] = res; }
}

// ---- K3: fused flash-decode chunk kernel. grid = HKV*NCH, 256 threads.
__global__ __launch_bounds__(256, 2)
void k_flash(const float* __restrict__ qf,
             const float* __restrict__ kcache,  // [HKV][DH][CC]
             const float* __restrict__ vcache,  // [HKV][CC][DH]
             const float* __restrict__ mask,    // [CC+1]
             float* __restrict__ opart,         // [HQ][NCH][DH]
             float2* __restrict__ ml){          // [HQ][NCH]
  __shared__ float q_s[2][DH];
  __shared__ float sc_part[4][2][CHUNK];   // d-group partial dots
  __shared__ float p_s[2][CHUNK];
  __shared__ float part[2][8][DH];
  __shared__ float red[8];
  int kv = blockIdx.x >> 6, ch = blockIdx.x & 63;
  int c0 = ch << 8;
  int t = threadIdx.x;
  q_s[t >> 7][t & 127] = qf[(kv * 2 + (t >> 7)) * DH + (t & 127)];
  __syncthreads();
  const float scale = 0.08838834764831845f;  // 128^-0.5

  // ---- Phase A: QK^T. Thread (dg, ln): 4 consecutive positions, 32 dims.
  // Explicit 8-deep register batches to force loads in flight.
  {
    int dg = t >> 6, ln = t & 63;
    const float* kp = kcache + (size_t)kv * DH * CC + (size_t)(dg * 32) * CC + (c0 + ln * 4);
    float a00 = 0.f, a01 = 0.f, a02 = 0.f, a03 = 0.f;
    float a10 = 0.f, a11 = 0.f, a12 = 0.f, a13 = 0.f;
    #pragma unroll
    for (int r = 0; r < 4; ++r){
      float4 kk[8];
      #pragma unroll
      for (int j = 0; j < 8; ++j)
        kk[j] = *(const float4*)(kp + (size_t)(r * 8 + j) * CC);
      #pragma unroll
      for (int j = 0; j < 8; ++j){
        int dd = r * 8 + j;
        float q0 = q_s[0][dg * 32 + dd], q1 = q_s[1][dg * 32 + dd];
        a00 += q0 * kk[j].x; a01 += q0 * kk[j].y; a02 += q0 * kk[j].z; a03 += q0 * kk[j].w;
        a10 += q1 * kk[j].x; a11 += q1 * kk[j].y; a12 += q1 * kk[j].z; a13 += q1 * kk[j].w;
      }
    }
    *(float4*)&sc_part[dg][0][ln * 4] = make_float4(a00, a01, a02, a03);
    *(float4*)&sc_part[dg][1][ln * 4] = make_float4(a10, a11, a12, a13);
  }
  __syncthreads();

  // ---- Phase B: combine partial dots, chunk softmax (m, l), p_s = exp(s-m).
  float s0, s1;
  {
    float mk = mask[c0 + t];
    s0 = (sc_part[0][0][t] + sc_part[1][0][t] + sc_part[2][0][t] + sc_part[3][0][t]) * scale + mk;
    s1 = (sc_part[0][1][t] + sc_part[1][1][t] + sc_part[2][1][t] + sc_part[3][1][t]) * scale + mk;
  }
  int wv = t >> 6, ln = t & 63;
  float lmax0 = s0, lmax1 = s1;
  #pragma unroll
  for (int off = 32; off; off >>= 1){
    lmax0 = fmaxf(lmax0, __shfl_down(lmax0, off, 64));
    lmax1 = fmaxf(lmax1, __shfl_down(lmax1, off, 64));
  }
  if (ln == 0){ red[wv] = lmax0; red[4 + wv] = lmax1; }
  __syncthreads();
  float m0 = fmaxf(fmaxf(red[0], red[1]), fmaxf(red[2], red[3]));
  float m1 = fmaxf(fmaxf(red[4], red[5]), fmaxf(red[6], red[7]));
  float p0 = __expf(s0 - m0);
  float p1 = __expf(s1 - m1);
  p_s[0][t] = p0;
  p_s[1][t] = p1;
  float ls0 = p0, ls1 = p1;
  #pragma unroll
  for (int off = 32; off; off >>= 1){
    ls0 += __shfl_down(ls0, off, 64);
    ls1 += __shfl_down(ls1, off, 64);
  }
  __syncthreads();
  if (ln == 0){ red[wv] = ls0; red[4 + wv] = ls1; }
  __syncthreads();
  if (t == 0){
    float l0 = red[0] + red[1] + red[2] + red[3];
    float l1 = red[4] + red[5] + red[6] + red[7];
    ml[(size_t)(kv * 2)     * NCH + ch] = make_float2(m0, l0);
    ml[(size_t)(kv * 2 + 1) * NCH + ch] = make_float2(m1, l1);
  }

  // ---- Phase C: partial O = sum_c p[c]*V[c][:]. 8 slices x 32 dim-threads.
  {
    int s = t >> 5, d4 = (t & 31) * 4;
    const float* vbase = vcache + (size_t)kv * CC * DH + d4;
    float4 a0 = make_float4(0.f, 0.f, 0.f, 0.f);
    float4 a1 = make_float4(0.f, 0.f, 0.f, 0.f);
    #pragma unroll
    for (int r = 0; r < 4; ++r){
      float4 vv[8];
      #pragma unroll
      for (int j = 0; j < 8; ++j){
        int off = (r * 8 + j) * 8 + s;
        vv[j] = *(const float4*)(vbase + (size_t)(c0 + off) * DH);
      }
      #pragma unroll
      for (int j = 0; j < 8; ++j){
        int off = (r * 8 + j) * 8 + s;
        float pp0 = p_s[0][off];
        float pp1 = p_s[1][off];
        a0.x += pp0 * vv[j].x; a0.y += pp0 * vv[j].y; a0.z += pp0 * vv[j].z; a0.w += pp0 * vv[j].w;
        a1.x += pp1 * vv[j].x; a1.y += pp1 * vv[j].y; a1.z += pp1 * vv[j].z; a1.w += pp1 * vv[j].w;
      }
    }
    *(float4*)&part[0][s][d4] = a0;
    *(float4*)&part[1][s][d4] = a1;
  }
  __syncthreads();
  {
    int hh = t >> 7, d = t & 127;
    float o = 0.f;
    #pragma unroll
    for (int ss = 0; ss < 8; ++ss) o += part[hh][ss][d];
    int qh = kv * 2 + hh;
    opart[((size_t)qh * NCH + ch) * DH + d] = o;
  }
}

// ---- K4: combine chunk partials + new-token term -> attn_in. grid=HQ, 128 threads.
__global__ void k_combine(const float* __restrict__ opart,
                          const float2* __restrict__ ml,
                          const float* __restrict__ qf,
                          const float* __restrict__ kf,
                          const float* __restrict__ vnew,   // raw+3072: [HKV][DH]
                          const float* __restrict__ mask,
                          float* __restrict__ attn_in){
  __shared__ float red[2];
  int qh = blockIdx.x, d = threadIdx.x;
  int kv = qh >> 1;
  float M = -1e30f;
  #pragma unroll 8
  for (int ch = 0; ch < NCH; ++ch) M = fmaxf(M, ml[(size_t)qh * NCH + ch].x);
  float o = 0.f, L = 0.f;
  for (int ch = 0; ch < NCH; ++ch){
    float2 m = ml[(size_t)qh * NCH + ch];
    float w = __expf(m.x - M);
    L += m.y * w;
    o += w * opart[((size_t)qh * NCH + ch) * DH + d];
  }
  float prod = qf[qh * DH + d] * kf[kv * DH + d];
  float sum = prod;
  #pragma unroll
  for (int off = 32; off; off >>= 1) sum += __shfl_down(sum, off, 64);
  if ((d & 63) == 0) red[d >> 6] = sum;
  __syncthreads();
  float s_new = (red[0] + red[1]) * 0.08838834764831845f + mask[CC];
  float pn = __expf(s_new - M);
  L += pn;
  o += pn * vnew[kv * DH + d];
  attn_in[qh * DH + d] = o / L;
}

// ---- K5: o_proj GEMV. One wave per output element, batched weight stream.
__global__ __launch_bounds__(256, 4)
void k_oproj(const float* __restrict__ attn_in,
             const float* __restrict__ Wo,
             float* __restrict__ out){
  int wave = threadIdx.x >> 6, lane = threadIdx.x & 63;
  int e = blockIdx.x * 4 + wave;
  const float* W = Wo + (size_t)e * HID;
  float4 w[8];
  #pragma unroll
  for (int j = 0; j < 4; ++j){
    int base = (j * 64 + lane) * 8;
    w[2*j]   = *(const float4*)(W + base);
    w[2*j+1] = *(const float4*)(W + base + 4);
  }
  float acc = 0.f;
  #pragma unroll
  for (int j = 0; j < 4; ++j){
    int base = (j * 64 + lane) * 8;
    float4 a0 = *(const float4*)(attn_in + base);
    float4 a1 = *(const float4*)(attn_in + base + 4);
    acc += a0.x*w[2*j].x + a0.y*w[2*j].y + a0.z*w[2*j].z + a0.w*w[2*j].w
         + a1.x*w[2*j+1].x + a1.y*w[2*j+1].y + a1.z*w[2*j+1].z + a1.w*w[2*j+1].w;
  }
  #pragma unroll
  for (int off = 32; off; off >>= 1) acc += __shfl_down(acc, off, 64);
  if (lane == 0) out[e] = acc;
}

extern "C" void kernel_launch(void* const* d_in, const int* in_sizes, int n_in,
                              void* d_out, int out_size, void* d_ws, size_t ws_size,
                              hipStream_t stream){
  const float* x    = (const float*)d_in[0];
  const float* cosb = (const float*)d_in[1];
  const float* sinb = (const float*)d_in[2];
  const float* mask = (const float*)d_in[3];
  const float* kc   = (const float*)d_in[4];
  const float* vc   = (const float*)d_in[5];
  const float* Wq   = (const float*)d_in[6];
  const float* Wk   = (const float*)d_in[7];
  const float* Wv   = (const float*)d_in[8];
  const float* Wo   = (const float*)d_in[9];
  const float* qw   = (const float*)d_in[10];
  const float* kw   = (const float*)d_in[11];
  float* out = (float*)d_out;
  float* ws = (float*)d_ws;
  float* raw     = ws;                          // 4096
  float* qf      = ws + 4096;                   // 2048
  float* kf      = ws + 6144;                   // 1024
  float* opart   = ws + 8192;                   // 16*64*128 = 131072
  float2* ML     = (float2*)(ws + 139264);      // 16*64 float2
  float* attn_in = ws + 141312;                 // 2048

  k_qkv     <<<1024, 256, 0, stream>>>(x, Wq, Wk, Wv, raw);
  k_normrope<<<32,   128, 0, stream>>>(raw, cosb, sinb, qw, kw, qf, kf, out);
  k_flash   <<<HKV * NCH, 256, 0, stream>>>(qf, kc, vc, mask, opart, ML);
  k_combine <<<HQ, 128, 0, stream>>>(opart, ML, qf, kf, raw + 3072, mask, attn_in);
  k_oproj   <<<512, 256, 0, stream>>>(attn_in, Wo, out);
}